// Round 5
// baseline (1115.136 us; speedup 1.0000x reference)
//
#include <hip/hip_runtime.h>

// BatchedMonomialFactor round 5:
//  - Numerics: proven 6-product bf16x3 split (rounds 2/4 passed; 4-product
//    2-split flips argmaxes), base-2 sinkhorn.
//  - Structure: 128x256 block tile (mt=8) -> B loads + barriers per MFMA
//    halved vs round 2; K-chunk=64 (2 sub-steps per barrier pair); A staged
//    via global_load_lds width-16 into fragment-major LDS; B direct from
//    XCD-local L2 (r-grouped block swizzle, kept from round 4: FETCH 476->277MB).
//  - Prep kernels rewritten for contiguous 16B/lane stores (were 2B scatter).

#define D_MODEL 1024
#define RDIM 64
#define NBATCH 2048

#define XSZ 2097152                    // 2048*1024 elements (per plane)
#define WPSZ 16777216                  // 1024*16384 elements (per plane)
#define WDSZ 1048576                   // 1024*1024 elements (per plane)

#define OFF_XS   0u
#define OFF_WPS  12582912u             // 3*XSZ*2
#define OFF_WDS  113246208u            // OFF_WPS + 3*WPSZ*2
#define OFF_WAS  117440512u            // OFF_WDS + 2*WDSZ*2
#define WS_NEED  121634816u            // OFF_WAS + 2*WDSZ*2

#define LSCALE 2.8853900817779268f     // (1/TAU=2) * log2(e)

typedef __attribute__((ext_vector_type(8))) short short8;
typedef __attribute__((ext_vector_type(4))) float f32x4;
#define MFMA_BF16 __builtin_amdgcn_mfma_f32_16x16x32_bf16

// async global->LDS, 16B per lane; lds dest = uniform base + lane*16
#define GLOAD_LDS16(g, lp) __builtin_amdgcn_global_load_lds( \
    (const __attribute__((address_space(1))) unsigned int*)(g), \
    (__attribute__((address_space(3))) unsigned int*)(lp), 16, 0, 0)

__device__ __forceinline__ unsigned short f2bf_rne(float f) {
    unsigned u = __float_as_uint(f);
    unsigned r = (u + 0x7fffu + ((u >> 16) & 1u)) >> 16;
    return (unsigned short)r;
}
__device__ __forceinline__ float bf2f(unsigned short s) {
    return __uint_as_float(((unsigned)s) << 16);
}

// ---------------- prep: split x into 3 bf16 planes, float4-vectorized -------
__global__ void k_split_x(const float* __restrict__ x, unsigned short* __restrict__ XS) {
    const int i = (blockIdx.x * 256 + threadIdx.x) * 4;
    const float4 v = *(const float4*)(x + i);
    const float vv[4] = {v.x, v.y, v.z, v.w};
    unsigned short p1[4], p2[4], p3[4];
    #pragma unroll
    for (int e = 0; e < 4; e++) {
        const unsigned short s1 = f2bf_rne(vv[e]);
        const float r1 = vv[e] - bf2f(s1);
        const unsigned short s2 = f2bf_rne(r1);
        p1[e] = s1; p2[e] = s2; p3[e] = f2bf_rne(r1 - bf2f(s2));
    }
    #pragma unroll
    for (int e = 0; e < 4; e++) {
        XS[i + e] = p1[e];
        XS[XSZ + i + e] = p2[e];
        XS[2 * XSZ + i + e] = p3[e];
    }
}

// ---- prep: Wp[k][c] -> dst[s][r][ks][n][k]; 16B/lane contiguous stores ----
__global__ void k_split_w(const float* __restrict__ W, unsigned short* __restrict__ dst) {
    __shared__ float tile[32][72];
    const int t = threadIdx.x;
    const int c0 = blockIdx.x * 64;
    const int kt = blockIdx.y;
    {
        const int kr = t >> 3, cq = (t & 7) * 8;
        const float* src = W + (long)(kt * 32 + kr) * 16384 + c0 + cq;
        *(float4*)&tile[kr][cq]     = *(const float4*)src;
        *(float4*)&tile[kr][cq + 4] = *(const float4*)(src + 4);
    }
    __syncthreads();
    const int kq = t & 3, cl = t >> 2;          // cl 0..63
    const int c = c0 + cl;
    const int rr = c >> 8, nn = c & 255;
    short8 o1, o2, o3;
    #pragma unroll
    for (int j = 0; j < 8; j++) {
        const float v = tile[kq * 8 + j][cl];
        const unsigned short s1 = f2bf_rne(v);
        const float r1 = v - bf2f(s1);
        const unsigned short s2 = f2bf_rne(r1);
        o1[j] = (short)s1; o2[j] = (short)s2; o3[j] = (short)f2bf_rne(r1 - bf2f(s2));
    }
    const long off = (((long)(rr * 32 + kt) * 256) + nn) * 32 + kq * 8;
    *(short8*)(dst + off) = o1;
    *(short8*)(dst + WPSZ + off) = o2;
    *(short8*)(dst + 2 * (long)WPSZ + off) = o3;
}

// ---- prep: Wd/Wa -> [s][r][ks][n=16][k=32], 2 planes each -----------------
__global__ void k_split_w2(const float* __restrict__ Wd, const float* __restrict__ Wa,
                           unsigned short* __restrict__ WDS_, unsigned short* __restrict__ WAS_) {
    __shared__ float tile[32][72];
    const float* W = blockIdx.z ? Wa : Wd;
    unsigned short* dst = blockIdx.z ? WAS_ : WDS_;
    const int t = threadIdx.x;
    const int c0 = blockIdx.x * 64;
    const int kt = blockIdx.y;
    {
        const int kr = t >> 3, cq = (t & 7) * 8;
        const float* src = W + (long)(kt * 32 + kr) * 1024 + c0 + cq;
        *(float4*)&tile[kr][cq]     = *(const float4*)src;
        *(float4*)&tile[kr][cq + 4] = *(const float4*)(src + 4);
    }
    __syncthreads();
    const int kq = t & 3, cl = t >> 2;
    const int c = c0 + cl;
    const int rr = c >> 4, nn = c & 15;
    short8 o1, o2;
    #pragma unroll
    for (int j = 0; j < 8; j++) {
        const float v = tile[kq * 8 + j][cl];
        const unsigned short s1 = f2bf_rne(v);
        o1[j] = (short)s1;
        o2[j] = (short)f2bf_rne(v - bf2f(s1));
    }
    const int off = ((rr * 32 + kt) * 16 + nn) * 32 + kq * 8;
    *(short8*)(dst + off) = o1;
    *(short8*)(dst + WDSZ + off) = o2;
}

// ---------------- main fused MFMA kernel ------------------------------------
// block tile: 128 batch rows x 256 perm cols (one r). grid 1024.
__global__ __launch_bounds__(256, 2)
void bmf_mfma_kernel(const unsigned short* __restrict__ XS,
                     const unsigned short* __restrict__ WPS,
                     const unsigned short* __restrict__ WDS,
                     const unsigned short* __restrict__ WAS,
                     const float* __restrict__ h,
                     float* __restrict__ out)
{
    // 67584 B LDS. GEMM phase: first 49152 B = A frags, region
    // [(p*2+sub)*4+quad] of 2048 B = rows 0..127 x 16 B. Epilogue aliases.
    __shared__ __align__(16) float sm[16896];
    char* smc   = (char*)sm;
    float* la   = sm;                           // [32][272] = 8704 f
    float* dval = sm + 8704;                    // [2048]
    float* aval = dval + 2048;                  // [2048]
    float* hv   = aval + 2048;                  // [2048]
    float* hpm  = hv + 2048;                    // [2048] -> 16896

    const int t = threadIdx.x;
    const int l = t & 63;
    const int w = t >> 6;                       // wave 0..3
    const int bid = blockIdx.x;
    // XCD swizzle: 16 bt-blocks of one r land on one XCD (bid&7)
    const int r  = ((bid >> 7) << 3) | (bid & 7);
    const int bt = (bid >> 3) & 15;
    const int b0 = bt * 128;
    const int quad = l >> 4, l15 = l & 15;

    f32x4 acc[8][4];
    f32x4 acc2[4];
    #pragma unroll
    for (int a = 0; a < 8; a++)
        #pragma unroll
        for (int b = 0; b < 4; b++) acc[a][b] = (f32x4){0.f, 0.f, 0.f, 0.f};
    #pragma unroll
    for (int a = 0; a < 4; a++) acc2[a] = (f32x4){0.f, 0.f, 0.f, 0.f};

    const int isAlpha = w >> 1;                 // waves 2,3 -> alpha
    const int rowHalf = w & 1;                  // rows 64*rowHalf..+63 for acc2
    const unsigned short* WX = isAlpha ? WAS : WDS;

    // B: [r][ks][n=256][k=32]; lane at n=(w*4+n)*16+l15, k=quad*8
    const unsigned short* bP = WPS + r * 262144 + ((w * 4) * 16 + l15) * 32 + quad * 8;
    const unsigned short* wP = WX + r * 16384 + l15 * 32 + quad * 8;

    for (int kc = 0; kc < 16; ++kc) {
        // ---- stage A chunk (3 planes x 128 rows x 64 k) via global_load_lds.
        // slot = ((p*2+sub)*4+quad)*2 + hf; wave w issues slots w*12..w*12+11;
        // lane l -> global row b0+hf*64+l, lds off slot*1024 + l*16.
        #pragma unroll
        for (int s = 0; s < 12; ++s) {
            const int slot = w * 12 + s;
            const int hf = slot & 1;
            const int reg = slot >> 1;
            const int q_ = reg & 3;
            const int ps = reg >> 2;            // p*2+sub
            const unsigned short* g = XS + (ps >> 1) * XSZ
                + (b0 + hf * 64 + l) * 1024 + kc * 64 + (ps & 1) * 32 + q_ * 8;
            GLOAD_LDS16(g, smc + slot * 1024);
        }
        __syncthreads();
        // ---- compute 2 sub-steps of K=32 ----
        #pragma unroll
        for (int sb = 0; sb < 2; ++sb) {
            const int ks = kc * 2 + sb;
            const unsigned short* bS = bP + ks * 8192;
            short8 bf0[4], bf1[4], bf2[4];
            #pragma unroll
            for (int n = 0; n < 4; n++) {
                bf0[n] = *(const short8*)(bS + n * 512);
                bf1[n] = *(const short8*)(bS + n * 512 + WPSZ);
                bf2[n] = *(const short8*)(bS + n * 512 + 2 * (long)WPSZ);
            }
            const short8 wf0 = *(const short8*)(wP + ks * 512);
            const short8 wf1 = *(const short8*)(wP + ks * 512 + WDSZ);
            #pragma unroll
            for (int mt = 0; mt < 8; mt++) {
                const int ro = (mt * 16 + l15) * 16;
                const short8 a0 = *(const short8*)(smc + ((0 * 2 + sb) * 4 + quad) * 2048 + ro);
                const short8 a1 = *(const short8*)(smc + ((1 * 2 + sb) * 4 + quad) * 2048 + ro);
                const short8 a2 = *(const short8*)(smc + ((2 * 2 + sb) * 4 + quad) * 2048 + ro);
                #pragma unroll
                for (int n = 0; n < 4; n++) {
                    f32x4 c = acc[mt][n];
                    c = MFMA_BF16(a0, bf0[n], c, 0, 0, 0);
                    c = MFMA_BF16(a0, bf1[n], c, 0, 0, 0);
                    c = MFMA_BF16(a1, bf0[n], c, 0, 0, 0);
                    c = MFMA_BF16(a0, bf2[n], c, 0, 0, 0);
                    c = MFMA_BF16(a1, bf1[n], c, 0, 0, 0);
                    c = MFMA_BF16(a2, bf0[n], c, 0, 0, 0);
                    acc[mt][n] = c;
                }
                if ((mt >> 2) == rowHalf) {
                    const int mi = mt & 3;
                    f32x4 c2 = acc2[mi];
                    c2 = MFMA_BF16(a0, wf0, c2, 0, 0, 0);
                    c2 = MFMA_BF16(a0, wf1, c2, 0, 0, 0);
                    c2 = MFMA_BF16(a1, wf0, c2, 0, 0, 0);
                    acc2[mi] = c2;
                }
            }
        }
        __syncthreads();
    }

    // ---- persist diag/alpha pre-activations (C/D: row=quad*4+q, col=l15) ----
    {
        float* arr = isAlpha ? aval : dval;
        #pragma unroll
        for (int mi = 0; mi < 4; mi++) {
            #pragma unroll
            for (int q = 0; q < 4; q++) {
                const int row = (rowHalf * 4 + mi) * 16 + quad * 4 + q;
                arr[row * 16 + l15] = acc2[mi][q];
            }
        }
    }
    // ---- stage h, zero h_permuted (128 rows x 16) ----
    #pragma unroll
    for (int q = 0; q < 8; q++) {
        const int id  = t + 256 * q;
        const int row = id >> 4, j = id & 15;
        hv[id]  = h[(long)(b0 + row) * D_MODEL + r * 16 + j];
        hpm[id] = 0.f;
    }
    __syncthreads();

    // ---- sinkhorn (base-2) + argmax + scatter, 4 chunks of 32 matrices -----
    for (int ch = 0; ch < 4; ++ch) {
        #pragma unroll
        for (int mi = 0; mi < 2; mi++) {
            const int mt = ch * 2 + mi;
            #pragma unroll
            for (int n = 0; n < 4; n++) {
                #pragma unroll
                for (int q = 0; q < 4; q++) {
                    const int ml = mi * 16 + quad * 4 + q;
                    la[ml * 272 + (w * 4 + n) * 17 + l15] = acc[mt][n][q] * LSCALE;
                }
            }
        }
        __syncthreads();

        for (int it = 0; it < 5; ++it) {
            #pragma unroll
            for (int q = 0; q < 2; q++) {
                const int id = t + 256 * q;
                const int m = id >> 4, i = id & 15;
                float* rowp = la + m * 272 + i * 17;
                float mx = rowp[0];
                #pragma unroll
                for (int j = 1; j < 16; j++) mx = fmaxf(mx, rowp[j]);
                float s = 0.f;
                #pragma unroll
                for (int j = 0; j < 16; j++) s += exp2f(rowp[j] - mx);
                const float lse = mx + log2f(s);
                #pragma unroll
                for (int j = 0; j < 16; j++) rowp[j] -= lse;
            }
            __syncthreads();
            #pragma unroll
            for (int q = 0; q < 2; q++) {
                const int id = t + 256 * q;
                const int m = id >> 4, j = id & 15;
                float* colp = la + m * 272 + j;
                float mx = colp[0];
                #pragma unroll
                for (int i = 1; i < 16; i++) mx = fmaxf(mx, colp[i * 17]);
                float s = 0.f;
                #pragma unroll
                for (int i = 0; i < 16; i++) s += exp2f(colp[i * 17] - mx);
                const float lse = mx + log2f(s);
                #pragma unroll
                for (int i = 0; i < 16; i++) colp[i * 17] -= lse;
            }
            __syncthreads();
        }
        #pragma unroll
        for (int q = 0; q < 2; q++) {
            const int id = t + 256 * q;
            const int m = id >> 4, j = id & 15;
            const float* colp = la + m * 272 + j;
            float best = colp[0]; int bi = 0;
            #pragma unroll
            for (int i = 1; i < 16; i++) {
                const float v = colp[i * 17];
                if (v > best) { best = v; bi = i; }
            }
            const int gm = ch * 32 + m;
            atomicAdd(&hpm[gm * 16 + bi], hv[gm * 16 + j]);
        }
        __syncthreads();
    }

    // ---- final: out = sigmoid(A) * tanh(D) * h_permuted ----
    #pragma unroll
    for (int q = 0; q < 8; q++) {
        const int id  = t + 256 * q;
        const int row = id >> 4, i = id & 15;
        const float A  = aval[id];
        const float Dv = dval[id];
        const float sg = 1.0f / (1.0f + expf(-A));
        out[(long)(b0 + row) * D_MODEL + r * 16 + i] = sg * tanhf(Dv) * hpm[id];
    }
}

// ---------------- fallback: round-1 fp32 kernel (used if ws too small) ------
__global__ __launch_bounds__(256, 2)
void bmf_fused_kernel(const float* __restrict__ x,
                      const float* __restrict__ h,
                      const float* __restrict__ Wp,
                      const float* __restrict__ Wd,
                      const float* __restrict__ Wa,
                      float* __restrict__ out)
{
    __shared__ float sm[15488];
    float* xs   = sm;
    float* wsh  = sm + 32 * 68;
    float* w2s  = wsh + 32 * 256;
    float* la   = sm;
    float* dval = sm + 11392;
    float* aval = dval + 1024;
    float* hv   = aval + 1024;
    float* hpm  = hv + 1024;

    const int t   = threadIdx.x;
    const int bid = blockIdx.x;
    const int r   = bid >> 5;
    const int b0  = (bid & 31) * 64;
    const long rcol0 = (long)r * 256;

    const int tr  = t >> 5;
    const int tc  = t & 31;
    const int cAi = tc * 4;
    const int cBi = 128 + tc * 4;
    const int row2 = t >> 2;
    const int c2   = (t & 3) * 8;

    float acc[8][8];
    float acc2[8];
    #pragma unroll
    for (int i = 0; i < 8; i++) {
        acc2[i] = 0.f;
        #pragma unroll
        for (int j = 0; j < 8; j++) acc[i][j] = 0.f;
    }

    for (int ks = 0; ks < 32; ++ks) {
        const int k0 = ks * 32;
        {
            const int row = t >> 2, kq = t & 3;
            #pragma unroll
            for (int e = 0; e < 2; e++) {
                const int kk = kq * 4 + e * 16;
                const float4 g = *(const float4*)(x + (long)(b0 + row) * 1024 + k0 + kk);
                xs[(kk + 0) * 68 + row] = g.x;
                xs[(kk + 1) * 68 + row] = g.y;
                xs[(kk + 2) * 68 + row] = g.z;
                xs[(kk + 3) * 68 + row] = g.w;
            }
        }
        {
            const int rbase = t >> 6;
            const int colf  = (t & 63) * 4;
            #pragma unroll
            for (int rep = 0; rep < 8; rep++) {
                const int rowk = rbase + rep * 4;
                const float4 g = *(const float4*)(Wp + (long)(k0 + rowk) * 16384 + rcol0 + colf);
                *(float4*)(wsh + rowk * 256 + colf) = g;
            }
        }
        {
            const int kr = t >> 3;
            const int c  = (t & 7) * 4;
            const float* src = (c < 16)
                ? (Wd + (long)(k0 + kr) * 1024 + r * 16 + c)
                : (Wa + (long)(k0 + kr) * 1024 + r * 16 + (c - 16));
            const float4 g = *(const float4*)src;
            *(float4*)(w2s + kr * 32 + c) = g;
        }
        __syncthreads();
        #pragma unroll
        for (int kk = 0; kk < 32; ++kk) {
            const float4 xlo = *(const float4*)(xs + kk * 68 + tr * 8);
            const float4 xhi = *(const float4*)(xs + kk * 68 + tr * 8 + 4);
            const float4 wA  = *(const float4*)(wsh + kk * 256 + cAi);
            const float4 wB  = *(const float4*)(wsh + kk * 256 + cBi);
            const float xv[8] = {xlo.x, xlo.y, xlo.z, xlo.w, xhi.x, xhi.y, xhi.z, xhi.w};
            #pragma unroll
            for (int ri = 0; ri < 8; ri++) {
                acc[ri][0] += xv[ri] * wA.x; acc[ri][1] += xv[ri] * wA.y;
                acc[ri][2] += xv[ri] * wA.z; acc[ri][3] += xv[ri] * wA.w;
                acc[ri][4] += xv[ri] * wB.x; acc[ri][5] += xv[ri] * wB.y;
                acc[ri][6] += xv[ri] * wB.z; acc[ri][7] += xv[ri] * wB.w;
            }
            const float xv2 = xs[kk * 68 + row2];
            const float4 u0 = *(const float4*)(w2s + kk * 32 + c2);
            const float4 u1 = *(const float4*)(w2s + kk * 32 + c2 + 4);
            acc2[0] += xv2 * u0.x; acc2[1] += xv2 * u0.y;
            acc2[2] += xv2 * u0.z; acc2[3] += xv2 * u0.w;
            acc2[4] += xv2 * u1.x; acc2[5] += xv2 * u1.y;
            acc2[6] += xv2 * u1.z; acc2[7] += xv2 * u1.w;
        }
        __syncthreads();
    }

    #pragma unroll
    for (int e = 0; e < 8; e++) {
        const int c = c2 + e;
        if (c < 16) dval[row2 * 16 + c] = acc2[e];
        else        aval[row2 * 16 + (c - 16)] = acc2[e];
    }
    #pragma unroll
    for (int q = 0; q < 4; q++) {
        const int id  = t + 256 * q;
        const int row = id >> 4, j = id & 15;
        hv[id]  = h[(long)(b0 + row) * 1024 + r * 16 + j];
        hpm[id] = 0.f;
    }
    __syncthreads();

    for (int half = 0; half < 2; ++half) {
        if ((tr >> 2) == half) {
            const int mbase = (tr & 3) * 8;
            #pragma unroll
            for (int ri = 0; ri < 8; ri++) {
                const int m = mbase + ri;
                #pragma unroll
                for (int e = 0; e < 8; e++) {
                    const int col = (e < 4) ? (cAi + e) : (cBi + e - 4);
                    la[m * 272 + (col >> 4) * 17 + (col & 15)] = acc[ri][e] * 2.0f;
                }
            }
        }
        __syncthreads();

        for (int it = 0; it < 5; ++it) {
            #pragma unroll
            for (int q = 0; q < 2; q++) {
                const int id = t + 256 * q;
                const int m = id >> 4, i = id & 15;
                float* rowp = la + m * 272 + i * 17;
                float mx = rowp[0];
                #pragma unroll
                for (int j = 1; j < 16; j++) mx = fmaxf(mx, rowp[j]);
                float s = 0.f;
                #pragma unroll
                for (int j = 0; j < 16; j++) s += expf(rowp[j] - mx);
                const float lse = mx + logf(s);
                #pragma unroll
                for (int j = 0; j < 16; j++) rowp[j] -= lse;
            }
            __syncthreads();
            #pragma unroll
            for (int q = 0; q < 2; q++) {
                const int id = t + 256 * q;
                const int m = id >> 4, j = id & 15;
                float* colp = la + m * 272 + j;
                float mx = colp[0];
                #pragma unroll
                for (int i = 1; i < 16; i++) mx = fmaxf(mx, colp[i * 17]);
                float s = 0.f;
                #pragma unroll
                for (int i = 0; i < 16; i++) s += expf(colp[i * 17] - mx);
                const float lse = mx + logf(s);
                #pragma unroll
                for (int i = 0; i < 16; i++) colp[i * 17] -= lse;
            }
            __syncthreads();
        }
        #pragma unroll
        for (int q = 0; q < 2; q++) {
            const int id = t + 256 * q;
            const int m = id >> 4, j = id & 15;
            const float* colp = la + m * 272 + j;
            float best = colp[0]; int bi = 0;
            #pragma unroll
            for (int i = 1; i < 16; i++) {
                const float v = colp[i * 17];
                if (v > best) { best = v; bi = i; }
            }
            const int gm = half * 32 + m;
            atomicAdd(&hpm[gm * 16 + bi], hv[gm * 16 + j]);
        }
        __syncthreads();
    }

    #pragma unroll
    for (int q = 0; q < 4; q++) {
        const int id  = t + 256 * q;
        const int row = id >> 4, i = id & 15;
        const float A  = aval[id];
        const float Dv = dval[id];
        const float sg = 1.0f / (1.0f + expf(-A));
        out[(long)(b0 + row) * 1024 + r * 16 + i] = sg * tanhf(Dv) * hpm[id];
    }
}

extern "C" void kernel_launch(void* const* d_in, const int* in_sizes, int n_in,
                              void* d_out, int out_size, void* d_ws, size_t ws_size,
                              hipStream_t stream) {
    const float* x  = (const float*)d_in[0];
    const float* h  = (const float*)d_in[1];
    const float* Wp = (const float*)d_in[2];
    const float* Wd = (const float*)d_in[3];
    const float* Wa = (const float*)d_in[4];
    float* out = (float*)d_out;

    if (ws_size >= (size_t)WS_NEED) {
        unsigned short* XS  = (unsigned short*)((char*)d_ws + OFF_XS);
        unsigned short* WPS = (unsigned short*)((char*)d_ws + OFF_WPS);
        unsigned short* WDS = (unsigned short*)((char*)d_ws + OFF_WDS);
        unsigned short* WAS = (unsigned short*)((char*)d_ws + OFF_WAS);
        k_split_x<<<dim3(XSZ / 1024), dim3(256), 0, stream>>>(x, XS);
        k_split_w<<<dim3(256, 32), dim3(256), 0, stream>>>(Wp, WPS);
        k_split_w2<<<dim3(16, 32, 2), dim3(256), 0, stream>>>(Wd, Wa, WDS, WAS);
        bmf_mfma_kernel<<<dim3(1024), dim3(256), 0, stream>>>(XS, WPS, WDS, WAS, h, out);
    } else {
        bmf_fused_kernel<<<dim3(2048), dim3(256), 0, stream>>>(x, h, Wp, Wd, Wa, out);
    }
}